// Round 1
// baseline (501.769 us; speedup 1.0000x reference)
//
#include <hip/hip_runtime.h>
#include <float.h>
#include <stdint.h>

#define HH 128
#define NROWS 32768
#define KCODES 4096
#define CAPR 40

// fixed codebook i8 scale: 5.2 sigma covers max|w| over 512K N(0,1) w.h.p.;
// clamp + EXACT per-code error norms (prep) keep the window rigorous anyway.
#define SW_Q 0.040944882f      // 5.2/127
#define INV_SW_Q 24.423077f    // 127/5.2

typedef _Float16 half8 __attribute__((ext_vector_type(8)));
typedef _Float16 half4_t __attribute__((ext_vector_type(4)));
typedef float floatx4 __attribute__((ext_vector_type(4)));
typedef float floatx16 __attribute__((ext_vector_type(16)));
typedef char charx8 __attribute__((ext_vector_type(8)));
typedef char charx16 __attribute__((ext_vector_type(16)));
typedef int intx4 __attribute__((ext_vector_type(4)));
typedef int intx16 __attribute__((ext_vector_type(16)));

// order-preserving float<->uint key (handles negatives) for LDS atomicMin
__device__ __forceinline__ unsigned fkey(float f) {
    unsigned b = __float_as_uint(f);
    return b ^ ((unsigned)((int)b >> 31) | 0x80000000u);
}
__device__ __forceinline__ float funkey(unsigned k) {
    unsigned b = (k & 0x80000000u) ? (k ^ 0x80000000u) : ~k;
    return __uint_as_float(b);
}

// ---------------------------------------------------------------------------
// ws layout (bytes): 0 wq2R float[4096] (0.5*||w||^2, MFMA-C-register order) |
// 16384 whPart float[512] ([0:256) blockmax ||w||^2, [256:512) blockmax
// ||w - SW*iw||^2) | 18432 whiA int8[524288] (512 KB, A-frag order).
// whiA: chunk (cb = code>>5, s = h/32) = 1024 bytes; entry lane =
// khalf*32 + (code&31) (16 B) holds iw[code][s*32 + khalf*16 + 0..15].
// The SAME h->(khalf,byte) assignment is used for the z B-frags, so the
// mapping is correct for any within-operand byte permutation as long as the
// HW pairs A and B positions symmetrically (true for the whole MFMA family;
// validated for f16 32x32x16 by the previous kernel).
// wq2R[cb*32 + kh*16 + r] = 0.5*||w||^2 of code cb*32+(r&3)+8*(r>>2)+4*kh
// (m74/m101 C/D layout, dtype-independent).
// ---------------------------------------------------------------------------

__global__ __launch_bounds__(256) void vq_prep(const float* __restrict__ w,
        float* __restrict__ wq2R, char* __restrict__ whiA,
        float* __restrict__ whPart, float* __restrict__ loss_slot) {
    __shared__ float sWH[16];
    __shared__ float sWD[16];
    const int t = threadIdx.x;
    const int tid = blockIdx.x * 256 + t;
    if (tid == 0) loss_slot[0] = 0.0f;   // d_out poisoned 0xAA each launch
    const int c = tid >> 4, hg = tid & 15;
    const int s = hg >> 2, khalf = (hg >> 1) & 1, jo = hg & 1;

    const float4* src = reinterpret_cast<const float4*>(w + (size_t)c * HH + (hg << 3));
    float4 a = src[0], b = src[1];
    float fv[8] = {a.x, a.y, a.z, a.w, b.x, b.y, b.z, b.w};
    float ssq = 0.f, dsq = 0.f;
    char qb[8];
#pragma unroll
    for (int i = 0; i < 8; ++i) {
        float v = fv[i];
        ssq = fmaf(v, v, ssq);
        float q = rintf(v * INV_SW_Q);
        q = fminf(127.f, fmaxf(-127.f, q));
        float d = fmaf(-q, SW_Q, v);     // exact quant residual vs SW_Q*iw
        dsq = fmaf(d, d, dsq);
        qb[i] = (char)(int)q;
    }
    charx8 pack = {qb[0], qb[1], qb[2], qb[3], qb[4], qb[5], qb[6], qb[7]};
    *reinterpret_cast<charx8*>(&whiA[((size_t)(c >> 5) * 4 + s) * 1024
                                     + (((khalf << 5) | (c & 31)) << 4) + (jo << 3)]) = pack;

    ssq += __shfl_xor(ssq, 1, 64); dsq += __shfl_xor(dsq, 1, 64);
    ssq += __shfl_xor(ssq, 2, 64); dsq += __shfl_xor(dsq, 2, 64);
    ssq += __shfl_xor(ssq, 4, 64); dsq += __shfl_xor(dsq, 4, 64);
    ssq += __shfl_xor(ssq, 8, 64); dsq += __shfl_xor(dsq, 8, 64);
    if (hg == 0) {
        int co = c & 31;
        wq2R[((c >> 5) << 5) + (((co >> 2) & 1) << 4) + ((co & 3) | ((co >> 3) << 2))]
            = 0.5f * ssq;
        sWH[t >> 4] = ssq;
        sWD[t >> 4] = dsq;
    }
    __syncthreads();
    if (t == 0) {
        float mh = 0.f, md = 0.f;
#pragma unroll
        for (int i = 0; i < 16; ++i) { mh = fmaxf(mh, sWH[i]); md = fmaxf(md, sWD[i]); }
        whPart[blockIdx.x] = mh;
        whPart[256 + blockIdx.x] = md;
    }
}

// ---------------------------------------------------------------------------
// Fused: i8 candidate-collecting scan (4 KB/tile VMEM, wq2 from LDS)
// + exact fp32 eval of candidates + zq/loss epilogue. Block = 32 rows,
// 4 waves x 1024-code quarters; codes-as-M (A), z rows as B (lane-resident).
// ---------------------------------------------------------------------------
__global__ __launch_bounds__(256, 2) void vq_fused(
        const float* __restrict__ z, const float* __restrict__ w,
        const float* __restrict__ wq2R, const char* __restrict__ whiA,
        const float* __restrict__ whPart,
        float* __restrict__ out_zq, float* __restrict__ out_idx,
        float* __restrict__ out_loss) {
    __shared__ unsigned smin[32];
    __shared__ int rowcnt[32];
    __shared__ int rowovf[32];
    __shared__ int rowlist[32 * CAPR];
    __shared__ float swh[4], swd[4];
    __shared__ int fb[32];
    __shared__ float lred[4];
    __shared__ __align__(16) float swq[KCODES];   // 16 KB wq2R copy

    const int t = threadIdx.x;
    const int lane = t & 63, wid = t >> 6;
    const int n = lane & 31, kh = lane >> 5;
    const int rowBase = blockIdx.x * 32;

    // codebook stats partial reduce (2x256 partials from prep)
    float wp = whPart[t], wd2 = whPart[256 + t];
#pragma unroll
    for (int off = 1; off < 64; off <<= 1) {
        wp = fmaxf(wp, __shfl_xor(wp, off, 64));
        wd2 = fmaxf(wd2, __shfl_xor(wd2, off, 64));
    }
    if (lane == 0) { swh[wid] = wp; swd[wid] = wd2; }
    if (t < 32) { smin[t] = 0xFFFFFFFFu; rowcnt[t] = 0; rowovf[t] = 0; }

    // stage wq2R into LDS (broadcast reads in the scan are then free)
    {
        const float4* g4 = reinterpret_cast<const float4*>(wq2R);
        float4* s4 = reinterpret_cast<float4*>(swq);
#pragma unroll
        for (int i = 0; i < 4; ++i) s4[i * 256 + t] = g4[i * 256 + t];
    }

    // ---- stage z: per-row i8 B-frags (row = n, k-half = kh) + exact norms ----
    const float* zr = z + (size_t)(rowBase + n) * HH + (kh << 4);
    float mx = 0.f, zn2 = 0.f;
#pragma unroll
    for (int u = 0; u < 16; ++u) {
        float4 a = *reinterpret_cast<const float4*>(zr + ((u >> 2) << 5) + ((u & 3) << 2));
        zn2 = fmaf(a.x, a.x, zn2); zn2 = fmaf(a.y, a.y, zn2);
        zn2 = fmaf(a.z, a.z, zn2); zn2 = fmaf(a.w, a.w, zn2);
        mx = fmaxf(mx, fmaxf(fmaxf(fabsf(a.x), fabsf(a.y)),
                             fmaxf(fabsf(a.z), fabsf(a.w))));
    }
    zn2 += __shfl_xor(zn2, 32, 64);
    mx = fmaxf(mx, __shfl_xor(mx, 32, 64));     // row max over both k-halves
    const float sZ = fmaxf(mx, 1e-20f) * (1.0f / 127.0f);
    const float invSZ = 1.0f / sZ;

    intx4 zb8[4];
    float zl2 = 0.f;
#pragma unroll
    for (int s = 0; s < 4; ++s) {
        charx16 cv;
#pragma unroll
        for (int q = 0; q < 4; ++q) {
            float4 a = *reinterpret_cast<const float4*>(zr + (s << 5) + (q << 2));
            float q0 = rintf(a.x * invSZ), q1 = rintf(a.y * invSZ);
            float q2 = rintf(a.z * invSZ), q3 = rintf(a.w * invSZ);
            float d0 = fmaf(-q0, sZ, a.x), d1 = fmaf(-q1, sZ, a.y);
            float d2 = fmaf(-q2, sZ, a.z), d3 = fmaf(-q3, sZ, a.w);
            zl2 = fmaf(d0, d0, zl2); zl2 = fmaf(d1, d1, zl2);
            zl2 = fmaf(d2, d2, zl2); zl2 = fmaf(d3, d3, zl2);
            cv[q * 4 + 0] = (char)(int)q0; cv[q * 4 + 1] = (char)(int)q1;
            cv[q * 4 + 2] = (char)(int)q2; cv[q * 4 + 3] = (char)(int)q3;
        }
        zb8[s] = __builtin_bit_cast(intx4, cv);
    }
    zl2 += __shfl_xor(zl2, 32, 64);

    __syncthreads();   // smin/cnt init + swh/swd + swq visible

    // rigorous window: |d/2_true - est| <= E with
    // E = ||z - sZ*iz||*||SW*iw||max + ||z||*||w - SW*iw||max + fp slack.
    // accept if est < runmin + thrw, thrw > 2E => true argmin always collected;
    // non-collected codes strictly worse in exact arithmetic.
    float WH  = sqrtf(fmaxf(fmaxf(swh[0], swh[1]), fmaxf(swh[2], swh[3])));
    float wDm = sqrtf(fmaxf(fmaxf(swd[0], swd[1]), fmaxf(swd[2], swd[3])));
    float znr = sqrtf(zn2), zdr = sqrtf(zl2);
    float E = zdr * (WH + wDm) * 1.01f + znr * wDm * 1.01f
            + (znr + zdr) * 1e-6f + 5e-3f;
    float thrw = 2.0f * E * 1.05f + 0.02f;
    const float nszw = -(sZ * SW_Q);   // est = wq2 - sZ*SW*idot

    const intx4* A4 = reinterpret_cast<const intx4*>(whiA);
    const int cb0 = wid << 5;
    float m1 = FLT_MAX;
    float m1pub = FLT_MAX;

    intx4 afA[4], afB[4];
    {
        const intx4* ap = A4 + (size_t)cb0 * 256 + lane;
#pragma unroll
        for (int p = 0; p < 4; ++p) afA[p] = ap[p * 64];
    }

    auto body = [&](int it, intx4 (&cur)[4], intx4 (&nxt)[4]) {
        const int cb = cb0 + ((it < 32) ? it : 0);
        if (it < 32) {
            const int cbn = cb0 + ((it + 1) & 31);
            const intx4* ap = A4 + (size_t)cbn * 256 + lane;
#pragma unroll
            for (int p = 0; p < 4; ++p) nxt[p] = ap[p * 64];
        }
        intx16 acc = {0,0,0,0,0,0,0,0,0,0,0,0,0,0,0,0};
#pragma unroll
        for (int s = 0; s < 4; ++s)
            acc = __builtin_amdgcn_mfma_i32_32x32x32_i8(cur[s], zb8[s], acc, 0, 0, 0);

        const float4* wqp = reinterpret_cast<const float4*>(&swq[(cb << 5) + (kh << 4)]);
        float4 wa = wqp[0], wb = wqp[1], wcq = wqp[2], wdq = wqp[3];
        float est[16];
        est[0]  = fmaf(nszw, (float)acc[0],  wa.x);
        est[1]  = fmaf(nszw, (float)acc[1],  wa.y);
        est[2]  = fmaf(nszw, (float)acc[2],  wa.z);
        est[3]  = fmaf(nszw, (float)acc[3],  wa.w);
        est[4]  = fmaf(nszw, (float)acc[4],  wb.x);
        est[5]  = fmaf(nszw, (float)acc[5],  wb.y);
        est[6]  = fmaf(nszw, (float)acc[6],  wb.z);
        est[7]  = fmaf(nszw, (float)acc[7],  wb.w);
        est[8]  = fmaf(nszw, (float)acc[8],  wcq.x);
        est[9]  = fmaf(nszw, (float)acc[9],  wcq.y);
        est[10] = fmaf(nszw, (float)acc[10], wcq.z);
        est[11] = fmaf(nszw, (float)acc[11], wcq.w);
        est[12] = fmaf(nszw, (float)acc[12], wdq.x);
        est[13] = fmaf(nszw, (float)acc[13], wdq.y);
        est[14] = fmaf(nszw, (float)acc[14], wdq.z);
        est[15] = fmaf(nszw, (float)acc[15], wdq.w);

        float t00 = fminf(est[0],  est[1]),  t01 = fminf(est[2],  est[3]);
        float t02 = fminf(est[4],  est[5]),  t03 = fminf(est[6],  est[7]);
        float t04 = fminf(est[8],  est[9]),  t05 = fminf(est[10], est[11]);
        float t06 = fminf(est[12], est[13]), t07 = fminf(est[14], est[15]);
        float tmin = fminf(fminf(fminf(t00, t01), fminf(t02, t03)),
                           fminf(fminf(t04, t05), fminf(t06, t07)));
        m1 = fminf(m1, tmin);
        if (m1 < m1pub) { atomicMin(&smin[n], fkey(m1)); m1pub = m1; }
        if (it > 0) {   // tile 0 collected on the it==32 re-pass (warm bound)
            float sh = funkey(((volatile unsigned*)smin)[n]);
            float bound = fminf(sh, m1) + thrw;
            if (tmin < bound) {
#pragma unroll
                for (int r = 0; r < 16; ++r) {
                    if (est[r] < bound) {
                        int code = (cb << 5) + (r & 3) + ((r >> 2) << 3) + (kh << 2);
                        int ix = atomicAdd(&rowcnt[n], 1);
                        if (ix < CAPR) rowlist[n * CAPR + ix] = code;
                        else rowovf[n] = 1;
                    }
                }
            }
        }
    };

#pragma unroll 1
    for (int itp = 0; itp < 16; ++itp) {
        body(2 * itp,     afA, afB);
        body(2 * itp + 1, afB, afA);
    }
    body(32, afA, afB);   // re-pass tile 0
    __syncthreads();

    // ---- exact fp32 eval of candidates (8 threads per row) ----
    {
        const int erow = t >> 3, eq = t & 7;
        int cnt = rowcnt[erow];
        bool ovf = (rowovf[erow] != 0) || (cnt > CAPR) || (cnt == 0);
        if (cnt > CAPR) cnt = CAPR;
        if (ovf) {
            if (eq == 0) rowovf[erow] = 1;
        } else {
            const float* zs = z + (size_t)(rowBase + erow) * HH + (eq << 4);
            float4 za = *reinterpret_cast<const float4*>(zs);
            float4 zb4 = *reinterpret_cast<const float4*>(zs + 4);
            float4 zc = *reinterpret_cast<const float4*>(zs + 8);
            float4 zd = *reinterpret_cast<const float4*>(zs + 12);
            float bd = FLT_MAX; int bc = 0x7fffffff;
            for (int j = 0; j < cnt; ++j) {
                int c = rowlist[erow * CAPR + j];
                const float* wr = w + (size_t)c * HH + (eq << 4);
                float4 wa = *reinterpret_cast<const float4*>(wr);
                float4 wb = *reinterpret_cast<const float4*>(wr + 4);
                float4 wc = *reinterpret_cast<const float4*>(wr + 8);
                float4 wd = *reinterpret_cast<const float4*>(wr + 12);
                float dot = 0.f;
                dot = fmaf(za.x,wa.x,dot); dot = fmaf(za.y,wa.y,dot);
                dot = fmaf(za.z,wa.z,dot); dot = fmaf(za.w,wa.w,dot);
                dot = fmaf(zb4.x,wb.x,dot); dot = fmaf(zb4.y,wb.y,dot);
                dot = fmaf(zb4.z,wb.z,dot); dot = fmaf(zb4.w,wb.w,dot);
                dot = fmaf(zc.x,wc.x,dot); dot = fmaf(zc.y,wc.y,dot);
                dot = fmaf(zc.z,wc.z,dot); dot = fmaf(zc.w,wc.w,dot);
                dot = fmaf(zd.x,wd.x,dot); dot = fmaf(zd.y,wd.y,dot);
                dot = fmaf(zd.z,wd.z,dot); dot = fmaf(zd.w,wd.w,dot);
                dot += __shfl_xor(dot, 1, 64);
                dot += __shfl_xor(dot, 2, 64);
                dot += __shfl_xor(dot, 4, 64);
                int co = c & 31;
                float wq2v = swq[((c >> 5) << 5) + (((co >> 2) & 1) << 4)
                                 + ((co & 3) | ((co >> 3) << 2))];
                float d2 = wq2v - dot;
                if (d2 < bd || (d2 == bd && c < bc)) { bd = d2; bc = c; }
            }
            if (eq == 0) { fb[erow] = bc; out_idx[rowBase + erow] = (float)bc; }
        }
    }
    __syncthreads();

    // ---- rigorous fallback: full exact scan for overflow rows (≈never) ----
    if (wid == 0) {
        for (int rr = 0; rr < 32; ++rr) {
            if (rowovf[rr] == 0) continue;
            const float* zrow = z + (size_t)(rowBase + rr) * HH;
            float bd = FLT_MAX; int bc = 0x7fffffff;
            for (int kq = 0; kq < 64; ++kq) {
                int c = (kq << 6) + lane;
                const float* wr = w + (size_t)c * HH;
                float dot = 0.f;
                for (int h4 = 0; h4 < 32; ++h4) {
                    float4 wv = *reinterpret_cast<const float4*>(wr + (h4 << 2));
                    float4 zv = *reinterpret_cast<const float4*>(zrow + (h4 << 2));
                    dot = fmaf(zv.x,wv.x,dot); dot = fmaf(zv.y,wv.y,dot);
                    dot = fmaf(zv.z,wv.z,dot); dot = fmaf(zv.w,wv.w,dot);
                }
                int co = c & 31;
                float wq2v = swq[((c >> 5) << 5) + (((co >> 2) & 1) << 4)
                                 + ((co & 3) | ((co >> 3) << 2))];
                float d2 = wq2v - dot;
                if (d2 < bd || (d2 == bd && c < bc)) { bd = d2; bc = c; }
            }
#pragma unroll
            for (int off = 1; off < 64; off <<= 1) {
                float od = __shfl_xor(bd, off, 64);
                int oc = __shfl_xor(bc, off, 64);
                if (od < bd || (od == bd && oc < bc)) { bd = od; bc = oc; }
            }
            if (lane == 0) { fb[rr] = bc; out_idx[rowBase + rr] = (float)bc; }
        }
    }
    __syncthreads();

    // ---- zq gather + loss (proven epilogue) ----
    const float4* z4 = reinterpret_cast<const float4*>(z);
    float lsum = 0.f;
#pragma unroll
    for (int i = 0; i < 4; ++i) {
        int g = i * 256 + t;
        int r = g >> 5, f4 = g & 31;
        int code = fb[r];
        float4 wv = *reinterpret_cast<const float4*>(w + (size_t)code * HH + (f4 << 2));
        float4 zv = z4[(size_t)(rowBase + r) * 32 + f4];
        float dx = wv.x - zv.x, dy = wv.y - zv.y, dz = wv.z - zv.z, dw = wv.w - zv.w;
        lsum = fmaf(dx, dx, lsum); lsum = fmaf(dy, dy, lsum);
        lsum = fmaf(dz, dz, lsum); lsum = fmaf(dw, dw, lsum);
        *reinterpret_cast<float4*>(out_zq + (size_t)(rowBase + r) * HH + (f4 << 2)) = wv;
    }
#pragma unroll
    for (int off = 1; off < 64; off <<= 1) lsum += __shfl_xor(lsum, off, 64);
    if (lane == 0) lred[wid] = lsum;
    __syncthreads();
    if (t == 0) {
        float total = lred[0] + lred[1] + lred[2] + lred[3];
        atomicAdd(out_loss, total * (1.25f / 4194304.0f));  // (0.25+1)*mean, N*H
    }
}

// ---------------- fallback path (Round-2 kernels, proven) -------------------
__device__ __forceinline__ int plane_off_fb(int r, int hu) {
    return ((hu << 6) | (r ^ (hu & 7))) << 3;
}

__global__ __launch_bounds__(256) void vq_prep_fb(const float* __restrict__ w,
                                                  float* __restrict__ wsq,
                                                  float* __restrict__ loss_slot) {
    int c = blockIdx.x * 256 + threadIdx.x;
    if (c == 0) loss_slot[0] = 0.0f;
    if (c < KCODES) {
        const float4* row = reinterpret_cast<const float4*>(w + (size_t)c * HH);
        float s = 0.0f;
#pragma unroll
        for (int i = 0; i < HH / 4; ++i) {
            float4 v = row[i];
            s = fmaf(v.x, v.x, s); s = fmaf(v.y, v.y, s);
            s = fmaf(v.z, v.z, s); s = fmaf(v.w, v.w, s);
        }
        wsq[c] = s;
    }
}

__device__ __forceinline__ void stage_tile_fb(const float4* __restrict__ src4,
                                              ushort* lds, int hi_base, int lo_base,
                                              int t) {
#pragma unroll
    for (int p = 0; p < 8; ++p) {
        int g = p * 256 + t;
        int r = g >> 5, f4 = g & 31;
        float4 v = src4[g];
        _Float16 h0 = (_Float16)v.x, h1 = (_Float16)v.y,
                 h2 = (_Float16)v.z, h3 = (_Float16)v.w;
        half4_t hv = {h0, h1, h2, h3};
        half4_t lv = {(_Float16)(v.x - (float)h0), (_Float16)(v.y - (float)h1),
                      (_Float16)(v.z - (float)h2), (_Float16)(v.w - (float)h3)};
        int off = plane_off_fb(r, f4 >> 1) + ((f4 & 1) << 2);
        *reinterpret_cast<half4_t*>(&lds[hi_base + off]) = hv;
        *reinterpret_cast<half4_t*>(&lds[lo_base + off]) = lv;
    }
}

__global__ __launch_bounds__(256, 2) void vq_main_fb(const float* __restrict__ z,
                                                     const float* __restrict__ w,
                                                     const float* __restrict__ wsq,
                                                     float* __restrict__ out_zq,
                                                     float* __restrict__ out_idx,
                                                     float* __restrict__ out_loss) {
    __shared__ __align__(16) ushort lds[32768];
    const int t = threadIdx.x, lane = t & 63, wid = t >> 6;
    const int q = lane >> 4, m15 = lane & 15;
    const int wrow = (wid >> 1) << 5, wcol = (wid & 1) << 5;
    const int rowBase = blockIdx.x * 64;

    stage_tile_fb(reinterpret_cast<const float4*>(z + (size_t)rowBase * HH), lds, 0, 8192, t);

    float best[2][4]; int bidx[2][4];
#pragma unroll
    for (int mt = 0; mt < 2; ++mt)
#pragma unroll
        for (int rg = 0; rg < 4; ++rg) { best[mt][rg] = FLT_MAX; bidx[mt][rg] = 0; }

    const int ar0 = wrow + m15, bn0 = wcol + m15;

    for (int k0 = 0; k0 < KCODES; k0 += 64) {
        __syncthreads();
        stage_tile_fb(reinterpret_cast<const float4*>(w + (size_t)k0 * HH), lds, 16384, 24576, t);
        __syncthreads();
        floatx4 acc[2][2];
#pragma unroll
        for (int mt = 0; mt < 2; ++mt)
#pragma unroll
            for (int nt = 0; nt < 2; ++nt) acc[mt][nt] = (floatx4){0.f, 0.f, 0.f, 0.f};
#pragma unroll
        for (int c = 0; c < 4; ++c) {
            const int hu = (c << 2) + q;
            half8 zh0 = *reinterpret_cast<half8*>(&lds[plane_off_fb(ar0, hu)]);
            half8 zh1 = *reinterpret_cast<half8*>(&lds[plane_off_fb(ar0 + 16, hu)]);
            half8 zl0 = *reinterpret_cast<half8*>(&lds[8192 + plane_off_fb(ar0, hu)]);
            half8 zl1 = *reinterpret_cast<half8*>(&lds[8192 + plane_off_fb(ar0 + 16, hu)]);
            half8 wh0 = *reinterpret_cast<half8*>(&lds[16384 + plane_off_fb(bn0, hu)]);
            half8 wh1 = *reinterpret_cast<half8*>(&lds[16384 + plane_off_fb(bn0 + 16, hu)]);
            half8 wl0 = *reinterpret_cast<half8*>(&lds[24576 + plane_off_fb(bn0, hu)]);
            half8 wl1 = *reinterpret_cast<half8*>(&lds[24576 + plane_off_fb(bn0 + 16, hu)]);
            acc[0][0] = __builtin_amdgcn_mfma_f32_16x16x32_f16(zh0, wh0, acc[0][0], 0, 0, 0);
            acc[0][1] = __builtin_amdgcn_mfma_f32_16x16x32_f16(zh0, wh1, acc[0][1], 0, 0, 0);
            acc[1][0] = __builtin_amdgcn_mfma_f32_16x16x32_f16(zh1, wh0, acc[1][0], 0, 0, 0);
            acc[1][1] = __builtin_amdgcn_mfma_f32_16x16x32_f16(zh1, wh1, acc[1][1], 0, 0, 0);
            acc[0][0] = __builtin_amdgcn_mfma_f32_16x16x32_f16(zh0, wl0, acc[0][0], 0, 0, 0);
            acc[0][1] = __builtin_amdgcn_mfma_f32_16x16x32_f16(zh0, wl1, acc[0][1], 0, 0, 0);
            acc[1][0] = __builtin_amdgcn_mfma_f32_16x16x32_f16(zh1, wl0, acc[1][0], 0, 0, 0);
            acc[1][1] = __builtin_amdgcn_mfma_f32_16x16x32_f16(zh1, wl1, acc[1][1], 0, 0, 0);
            acc[0][0] = __builtin_amdgcn_mfma_f32_16x16x32_f16(zl0, wh0, acc[0][0], 0, 0, 0);
            acc[0][1] = __builtin_amdgcn_mfma_f32_16x16x32_f16(zl0, wh1, acc[0][1], 0, 0, 0);
            acc[1][0] = __builtin_amdgcn_mfma_f32_16x16x32_f16(zl1, wh0, acc[1][0], 0, 0, 0);
            acc[1][1] = __builtin_amdgcn_mfma_f32_16x16x32_f16(zl1, wh1, acc[1][1], 0, 0, 0);
        }
        float wq0 = wsq[k0 + bn0], wq1 = wsq[k0 + bn0 + 16];
#pragma unroll
        for (int mt = 0; mt < 2; ++mt)
#pragma unroll
            for (int nt = 0; nt < 2; ++nt) {
                int code = k0 + wcol + (nt << 4) + m15;
                float wqv = nt ? wq1 : wq0;
#pragma unroll
                for (int rg = 0; rg < 4; ++rg) {
                    float s = fmaf(-2.0f, acc[mt][nt][rg], wqv);
                    if (s < best[mt][rg]) { best[mt][rg] = s; bidx[mt][rg] = code; }
                }
            }
    }
#pragma unroll
    for (int off = 1; off < 16; off <<= 1)
#pragma unroll
        for (int mt = 0; mt < 2; ++mt)
#pragma unroll
            for (int rg = 0; rg < 4; ++rg) {
                float os = __shfl_xor(best[mt][rg], off, 64);
                int   oi = __shfl_xor(bidx[mt][rg], off, 64);
                if (os < best[mt][rg] || (os == best[mt][rg] && oi < bidx[mt][rg])) {
                    best[mt][rg] = os; bidx[mt][rg] = oi;
                }
            }
    float* epmin = reinterpret_cast<float*>(lds);
    int*   epidx = reinterpret_cast<int*>(reinterpret_cast<char*>(lds) + 512);
    int*   fbidx = reinterpret_cast<int*>(reinterpret_cast<char*>(lds) + 1024);
    float* lredf = reinterpret_cast<float*>(reinterpret_cast<char*>(lds) + 1280);
    __syncthreads();
    if (m15 == 0) {
        int g = wid & 1;
#pragma unroll
        for (int mt = 0; mt < 2; ++mt)
#pragma unroll
            for (int rg = 0; rg < 4; ++rg) {
                int row = wrow + (mt << 4) + (q << 2) + rg;
                epmin[g * 64 + row] = best[mt][rg];
                epidx[g * 64 + row] = bidx[mt][rg];
            }
    }
    __syncthreads();
    if (t < 64) {
        float s0 = epmin[t], s1 = epmin[64 + t];
        int   i0 = epidx[t], i1 = epidx[64 + t];
        int   fi = (s1 < s0 || (s1 == s0 && i1 < i0)) ? i1 : i0;
        fbidx[t] = fi;
        out_idx[rowBase + t] = (float)fi;
    }
    __syncthreads();
    const float4* z4 = reinterpret_cast<const float4*>(z);
    float lsum = 0.0f;
#pragma unroll
    for (int i = 0; i < 8; ++i) {
        int g = i * 256 + t;
        int r = g >> 5, f4 = g & 31;
        int code = fbidx[r];
        float4 wv = *reinterpret_cast<const float4*>(w + (size_t)code * HH + (f4 << 2));
        float4 zv = z4[(size_t)(rowBase + r) * 32 + f4];
        float dx = wv.x - zv.x, dy = wv.y - zv.y, dz = wv.z - zv.z, dw = wv.w - zv.w;
        lsum = fmaf(dx, dx, lsum); lsum = fmaf(dy, dy, lsum);
        lsum = fmaf(dz, dz, lsum); lsum = fmaf(dw, dw, lsum);
        *reinterpret_cast<float4*>(out_zq + (size_t)(rowBase + r) * HH + (f4 << 2)) = wv;
    }
#pragma unroll
    for (int off = 1; off < 64; off <<= 1) lsum += __shfl_xor(lsum, off, 64);
    if (lane == 0) lredf[wid] = lsum;
    __syncthreads();
    if (t == 0)
        atomicAdd(out_loss, (lredf[0] + lredf[1] + lredf[2] + lredf[3]) * (1.25f / 4194304.0f));
}

extern "C" void kernel_launch(void* const* d_in, const int* in_sizes, int n_in,
                              void* d_out, int out_size, void* d_ws, size_t ws_size,
                              hipStream_t stream) {
    (void)in_sizes; (void)n_in; (void)out_size;
    const float* z = (const float*)d_in[0];
    const float* w = (const float*)d_in[1];
    float* out      = (float*)d_out;
    float* out_zq   = out;
    float* out_idx  = out + (size_t)NROWS * HH;
    float* out_loss = out_idx + NROWS;

    char* wsb = (char*)d_ws;
    float* wq2R   = (float*)(wsb + 0);        // 16 KB
    float* whPart = (float*)(wsb + 16384);    // 2 KB (512 floats)
    char*  whiA   = (char*)(wsb + 18432);     // 512 KB i8 codes, A-frag order
    const size_t WS_NEED = 18432 + (size_t)KCODES * HH;

    if (ws_size >= WS_NEED) {
        vq_prep<<<256, 256, 0, stream>>>(w, wq2R, whiA, whPart, out_loss);
        vq_fused<<<NROWS / 32, 256, 0, stream>>>(z, w, wq2R, whiA, whPart,
                                                 out_zq, out_idx, out_loss);
    } else {
        float* wsq = (float*)d_ws;
        vq_prep_fb<<<KCODES / 256, 256, 0, stream>>>(w, wsq, out_loss);
        vq_main_fb<<<NROWS / 64, 256, 0, stream>>>(z, w, wsq, out_zq, out_idx, out_loss);
    }
}

// Round 2
// 178.146 us; speedup vs baseline: 2.8166x; 2.8166x over previous
//
#include <hip/hip_runtime.h>
#include <float.h>
#include <stdint.h>

#define HH 128
#define NROWS 32768
#define KCODES 4096
#define CAPR 64

// fixed codebook i8 scale: 5.2 sigma covers max|w| over 512K N(0,1) w.h.p.;
// clamp + EXACT per-code error norms (prep) keep the window rigorous anyway.
#define SW_Q 0.040944882f      // 5.2/127
#define INV_SW_Q 24.423077f    // 127/5.2

typedef _Float16 half8 __attribute__((ext_vector_type(8)));
typedef _Float16 half4_t __attribute__((ext_vector_type(4)));
typedef float floatx4 __attribute__((ext_vector_type(4)));
typedef float floatx16 __attribute__((ext_vector_type(16)));
typedef char charx8 __attribute__((ext_vector_type(8)));
typedef char charx16 __attribute__((ext_vector_type(16)));
typedef int intx4 __attribute__((ext_vector_type(4)));
typedef int intx16 __attribute__((ext_vector_type(16)));

// order-preserving float<->uint key (handles negatives) for LDS atomicMin
__device__ __forceinline__ unsigned fkey(float f) {
    unsigned b = __float_as_uint(f);
    return b ^ ((unsigned)((int)b >> 31) | 0x80000000u);
}
__device__ __forceinline__ float funkey(unsigned k) {
    unsigned b = (k & 0x80000000u) ? (k ^ 0x80000000u) : ~k;
    return __uint_as_float(b);
}

// ---------------------------------------------------------------------------
// ws layout (bytes): 0 wq2R float[4096] (0.5*||w||^2, MFMA-C-register order) |
// 16384 whPart float[512] ([0:256) blockmax ||w||^2, [256:512) blockmax
// ||w - SW*iw||^2) | 18432 whiA int8[524288] (512 KB, A-frag order).
// whiA: chunk (cb = code>>5, s = h/32) = 1024 bytes; entry lane =
// khalf*32 + (code&31) (16 B) holds iw[code][s*32 + khalf*16 + 0..15].
// Same h->(khalf,byte) assignment used for z B-frags (A/B symmetric mapping;
// validated by round-1 pass). wq2R[cb*32 + kh*16 + r] = 0.5*||w||^2 of code
// cb*32+(r&3)+8*(r>>2)+4*kh (m74/m101 C/D layout, dtype-independent).
// ---------------------------------------------------------------------------

__global__ __launch_bounds__(256) void vq_prep(const float* __restrict__ w,
        float* __restrict__ wq2R, char* __restrict__ whiA,
        float* __restrict__ whPart, float* __restrict__ loss_slot) {
    __shared__ float sWH[16];
    __shared__ float sWD[16];
    const int t = threadIdx.x;
    const int tid = blockIdx.x * 256 + t;
    if (tid == 0) loss_slot[0] = 0.0f;   // d_out poisoned 0xAA each launch
    const int c = tid >> 4, hg = tid & 15;
    const int s = hg >> 2, khalf = (hg >> 1) & 1, jo = hg & 1;

    const float4* src = reinterpret_cast<const float4*>(w + (size_t)c * HH + (hg << 3));
    float4 a = src[0], b = src[1];
    float fv[8] = {a.x, a.y, a.z, a.w, b.x, b.y, b.z, b.w};
    float ssq = 0.f, dsq = 0.f;
    char qb[8];
#pragma unroll
    for (int i = 0; i < 8; ++i) {
        float v = fv[i];
        ssq = fmaf(v, v, ssq);
        float q = rintf(v * INV_SW_Q);
        q = fminf(127.f, fmaxf(-127.f, q));
        float d = fmaf(-q, SW_Q, v);     // exact quant residual vs SW_Q*iw
        dsq = fmaf(d, d, dsq);
        qb[i] = (char)(int)q;
    }
    charx8 pack = {qb[0], qb[1], qb[2], qb[3], qb[4], qb[5], qb[6], qb[7]};
    *reinterpret_cast<charx8*>(&whiA[((size_t)(c >> 5) * 4 + s) * 1024
                                     + (((khalf << 5) | (c & 31)) << 4) + (jo << 3)]) = pack;

    ssq += __shfl_xor(ssq, 1, 64); dsq += __shfl_xor(dsq, 1, 64);
    ssq += __shfl_xor(ssq, 2, 64); dsq += __shfl_xor(dsq, 2, 64);
    ssq += __shfl_xor(ssq, 4, 64); dsq += __shfl_xor(dsq, 4, 64);
    ssq += __shfl_xor(ssq, 8, 64); dsq += __shfl_xor(dsq, 8, 64);
    if (hg == 0) {
        int co = c & 31;
        wq2R[((c >> 5) << 5) + (((co >> 2) & 1) << 4) + ((co & 3) | ((co >> 3) << 2))]
            = 0.5f * ssq;
        sWH[t >> 4] = ssq;
        sWD[t >> 4] = dsq;
    }
    __syncthreads();
    if (t == 0) {
        float mh = 0.f, md = 0.f;
#pragma unroll
        for (int i = 0; i < 16; ++i) { mh = fmaxf(mh, sWH[i]); md = fmaxf(md, sWD[i]); }
        whPart[blockIdx.x] = mh;
        whPart[256 + blockIdx.x] = md;
    }
}

// ---------------------------------------------------------------------------
// Fused: i8 candidate-collecting scan (4 KB/tile VMEM, wq2 from LDS)
// + exact fp32 eval of candidates + zq/loss epilogue. Block = 32 rows,
// 4 waves x 1024-code quarters; codes-as-M (A), z rows as B (lane-resident).
// Collection is reserve-then-store: 1 LDS atomic per triggered tile-check,
// not 16 chained ones (round-1 lesson: wave-level trigger rate is ~86%).
// ---------------------------------------------------------------------------
__global__ __launch_bounds__(256, 4) void vq_fused(
        const float* __restrict__ z, const float* __restrict__ w,
        const float* __restrict__ wq2R, const char* __restrict__ whiA,
        const float* __restrict__ whPart,
        float* __restrict__ out_zq, float* __restrict__ out_idx,
        float* __restrict__ out_loss) {
    __shared__ unsigned smin[32];
    __shared__ int rowcnt[32];
    __shared__ int rowovf[32];
    __shared__ int rowlist[32 * CAPR];
    __shared__ float swh[4], swd[4];
    __shared__ int fb[32];
    __shared__ float lred[4];
    __shared__ __align__(16) float swq[KCODES];   // 16 KB wq2R copy

    const int t = threadIdx.x;
    const int lane = t & 63, wid = t >> 6;
    const int n = lane & 31, kh = lane >> 5;
    const int rowBase = blockIdx.x * 32;

    // codebook stats partial reduce (2x256 partials from prep)
    float wp = whPart[t], wd2 = whPart[256 + t];
#pragma unroll
    for (int off = 1; off < 64; off <<= 1) {
        wp = fmaxf(wp, __shfl_xor(wp, off, 64));
        wd2 = fmaxf(wd2, __shfl_xor(wd2, off, 64));
    }
    if (lane == 0) { swh[wid] = wp; swd[wid] = wd2; }
    if (t < 32) { smin[t] = 0xFFFFFFFFu; rowcnt[t] = 0; rowovf[t] = 0; }

    // stage wq2R into LDS (broadcast reads in the scan are then free)
    {
        const float4* g4 = reinterpret_cast<const float4*>(wq2R);
        float4* s4 = reinterpret_cast<float4*>(swq);
#pragma unroll
        for (int i = 0; i < 4; ++i) s4[i * 256 + t] = g4[i * 256 + t];
    }

    // ---- stage z: per-row i8 B-frags (row = n, k-half = kh) + exact norms ----
    const float* zr = z + (size_t)(rowBase + n) * HH + (kh << 4);
    float mx = 0.f, zn2 = 0.f;
#pragma unroll
    for (int u = 0; u < 16; ++u) {
        float4 a = *reinterpret_cast<const float4*>(zr + ((u >> 2) << 5) + ((u & 3) << 2));
        zn2 = fmaf(a.x, a.x, zn2); zn2 = fmaf(a.y, a.y, zn2);
        zn2 = fmaf(a.z, a.z, zn2); zn2 = fmaf(a.w, a.w, zn2);
        mx = fmaxf(mx, fmaxf(fmaxf(fabsf(a.x), fabsf(a.y)),
                             fmaxf(fabsf(a.z), fabsf(a.w))));
    }
    zn2 += __shfl_xor(zn2, 32, 64);
    mx = fmaxf(mx, __shfl_xor(mx, 32, 64));     // row max over both k-halves
    const float sZ = fmaxf(mx, 1e-20f) * (1.0f / 127.0f);
    const float invSZ = 1.0f / sZ;

    intx4 zb8[4];
    float zl2 = 0.f;
#pragma unroll
    for (int s = 0; s < 4; ++s) {
        charx16 cv;
#pragma unroll
        for (int q = 0; q < 4; ++q) {
            float4 a = *reinterpret_cast<const float4*>(zr + (s << 5) + (q << 2));
            float q0 = rintf(a.x * invSZ), q1 = rintf(a.y * invSZ);
            float q2 = rintf(a.z * invSZ), q3 = rintf(a.w * invSZ);
            float d0 = fmaf(-q0, sZ, a.x), d1 = fmaf(-q1, sZ, a.y);
            float d2 = fmaf(-q2, sZ, a.z), d3 = fmaf(-q3, sZ, a.w);
            zl2 = fmaf(d0, d0, zl2); zl2 = fmaf(d1, d1, zl2);
            zl2 = fmaf(d2, d2, zl2); zl2 = fmaf(d3, d3, zl2);
            cv[q * 4 + 0] = (char)(int)q0; cv[q * 4 + 1] = (char)(int)q1;
            cv[q * 4 + 2] = (char)(int)q2; cv[q * 4 + 3] = (char)(int)q3;
        }
        zb8[s] = __builtin_bit_cast(intx4, cv);
    }
    zl2 += __shfl_xor(zl2, 32, 64);

    __syncthreads();   // smin/cnt init + swh/swd + swq visible

    // rigorous window: |d/2_true - est| <= E with
    // E = ||z - sZ*iz||*||SW*iw||max + ||z||*||w - SW*iw||max + fp slack.
    // accept if est < runmin + thrw, thrw > 2E => true argmin always collected;
    // non-collected codes strictly worse in exact arithmetic.
    float WH  = sqrtf(fmaxf(fmaxf(swh[0], swh[1]), fmaxf(swh[2], swh[3])));
    float wDm = sqrtf(fmaxf(fmaxf(swd[0], swd[1]), fmaxf(swd[2], swd[3])));
    float znr = sqrtf(zn2), zdr = sqrtf(zl2);
    float E = zdr * (WH + wDm) * 1.01f + znr * wDm * 1.01f
            + (znr + zdr) * 1e-6f + 5e-3f;
    float thrw = 2.0f * E * 1.05f + 0.02f;
    const float nszw = -(sZ * SW_Q);   // est = wq2 - sZ*SW*idot

    const intx4* A4 = reinterpret_cast<const intx4*>(whiA);
    const int cb0 = wid << 5;
    float m1 = FLT_MAX;
    float m1pub = FLT_MAX;

    intx4 afA[4], afB[4];
    {
        const intx4* ap = A4 + (size_t)cb0 * 256 + lane;
#pragma unroll
        for (int p = 0; p < 4; ++p) afA[p] = ap[p * 64];
    }

    auto body = [&](int it, intx4 (&cur)[4], intx4 (&nxt)[4]) {
        const int cb = cb0 + ((it < 32) ? it : 0);
        if (it < 32) {
            const int cbn = cb0 + ((it + 1) & 31);
            const intx4* ap = A4 + (size_t)cbn * 256 + lane;
#pragma unroll
            for (int p = 0; p < 4; ++p) nxt[p] = ap[p * 64];
        }
        intx16 acc = {0,0,0,0,0,0,0,0,0,0,0,0,0,0,0,0};
#pragma unroll
        for (int s = 0; s < 4; ++s)
            acc = __builtin_amdgcn_mfma_i32_32x32x32_i8(cur[s], zb8[s], acc, 0, 0, 0);

        const float4* wqp = reinterpret_cast<const float4*>(&swq[(cb << 5) + (kh << 4)]);
        float4 wa = wqp[0], wb = wqp[1], wcq = wqp[2], wdq = wqp[3];
        float est[16];
        est[0]  = fmaf(nszw, (float)acc[0],  wa.x);
        est[1]  = fmaf(nszw, (float)acc[1],  wa.y);
        est[2]  = fmaf(nszw, (float)acc[2],  wa.z);
        est[3]  = fmaf(nszw, (float)acc[3],  wa.w);
        est[4]  = fmaf(nszw, (float)acc[4],  wb.x);
        est[5]  = fmaf(nszw, (float)acc[5],  wb.y);
        est[6]  = fmaf(nszw, (float)acc[6],  wb.z);
        est[7]  = fmaf(nszw, (float)acc[7],  wb.w);
        est[8]  = fmaf(nszw, (float)acc[8],  wcq.x);
        est[9]  = fmaf(nszw, (float)acc[9],  wcq.y);
        est[10] = fmaf(nszw, (float)acc[10], wcq.z);
        est[11] = fmaf(nszw, (float)acc[11], wcq.w);
        est[12] = fmaf(nszw, (float)acc[12], wdq.x);
        est[13] = fmaf(nszw, (float)acc[13], wdq.y);
        est[14] = fmaf(nszw, (float)acc[14], wdq.z);
        est[15] = fmaf(nszw, (float)acc[15], wdq.w);

        float t00 = fminf(est[0],  est[1]),  t01 = fminf(est[2],  est[3]);
        float t02 = fminf(est[4],  est[5]),  t03 = fminf(est[6],  est[7]);
        float t04 = fminf(est[8],  est[9]),  t05 = fminf(est[10], est[11]);
        float t06 = fminf(est[12], est[13]), t07 = fminf(est[14], est[15]);
        float tmin = fminf(fminf(fminf(t00, t01), fminf(t02, t03)),
                           fminf(fminf(t04, t05), fminf(t06, t07)));
        m1 = fminf(m1, tmin);
        if (m1 < m1pub) { atomicMin(&smin[n], fkey(m1)); m1pub = m1; }
        if (it > 0) {   // tile 0 collected on the it==32 re-pass (warm bound)
            float sh = funkey(((volatile unsigned*)smin)[n]);
            float bound = fminf(sh, m1) + thrw;
            if (tmin < bound) {
                // reserve-then-store: ONE atomic, then pipelined plain stores
                unsigned cm = 0;
#pragma unroll
                for (int r = 0; r < 16; ++r)
                    if (est[r] < bound) cm |= (1u << r);
                int cc = __popc(cm);
                int ix = atomicAdd(&rowcnt[n], cc);
                if (ix + cc > CAPR) rowovf[n] = 1;
#pragma unroll
                for (int r = 0; r < 16; ++r) {
                    if (cm & (1u << r)) {
                        if (ix < CAPR)
                            rowlist[n * CAPR + ix] =
                                (cb << 5) + (r & 3) + ((r >> 2) << 3) + (kh << 2);
                        ++ix;
                    }
                }
            }
        }
    };

#pragma unroll 1
    for (int itp = 0; itp < 16; ++itp) {
        body(2 * itp,     afA, afB);
        body(2 * itp + 1, afB, afA);
    }
    body(32, afA, afB);   // re-pass tile 0
    __syncthreads();

    // ---- exact fp32 eval of candidates (8 threads per row) ----
    {
        const int erow = t >> 3, eq = t & 7;
        int cnt = rowcnt[erow];
        bool ovf = (rowovf[erow] != 0) || (cnt > CAPR) || (cnt == 0);
        if (cnt > CAPR) cnt = CAPR;
        if (ovf) {
            if (eq == 0) rowovf[erow] = 1;
        } else {
            const float* zs = z + (size_t)(rowBase + erow) * HH + (eq << 4);
            float4 za = *reinterpret_cast<const float4*>(zs);
            float4 zb4 = *reinterpret_cast<const float4*>(zs + 4);
            float4 zc = *reinterpret_cast<const float4*>(zs + 8);
            float4 zd = *reinterpret_cast<const float4*>(zs + 12);
            float bd = FLT_MAX; int bc = 0x7fffffff;
            for (int j = 0; j < cnt; ++j) {
                int c = rowlist[erow * CAPR + j];
                const float* wr = w + (size_t)c * HH + (eq << 4);
                float4 wa = *reinterpret_cast<const float4*>(wr);
                float4 wb = *reinterpret_cast<const float4*>(wr + 4);
                float4 wc = *reinterpret_cast<const float4*>(wr + 8);
                float4 wd = *reinterpret_cast<const float4*>(wr + 12);
                float dot = 0.f;
                dot = fmaf(za.x,wa.x,dot); dot = fmaf(za.y,wa.y,dot);
                dot = fmaf(za.z,wa.z,dot); dot = fmaf(za.w,wa.w,dot);
                dot = fmaf(zb4.x,wb.x,dot); dot = fmaf(zb4.y,wb.y,dot);
                dot = fmaf(zb4.z,wb.z,dot); dot = fmaf(zb4.w,wb.w,dot);
                dot = fmaf(zc.x,wc.x,dot); dot = fmaf(zc.y,wc.y,dot);
                dot = fmaf(zc.z,wc.z,dot); dot = fmaf(zc.w,wc.w,dot);
                dot = fmaf(zd.x,wd.x,dot); dot = fmaf(zd.y,wd.y,dot);
                dot = fmaf(zd.z,wd.z,dot); dot = fmaf(zd.w,wd.w,dot);
                dot += __shfl_xor(dot, 1, 64);
                dot += __shfl_xor(dot, 2, 64);
                dot += __shfl_xor(dot, 4, 64);
                int co = c & 31;
                float wq2v = swq[((c >> 5) << 5) + (((co >> 2) & 1) << 4)
                                 + ((co & 3) | ((co >> 3) << 2))];
                float d2 = wq2v - dot;
                if (d2 < bd || (d2 == bd && c < bc)) { bd = d2; bc = c; }
            }
            if (eq == 0) { fb[erow] = bc; out_idx[rowBase + erow] = (float)bc; }
        }
    }
    __syncthreads();

    // ---- rigorous fallback: full exact scan for overflow rows (≈never),
    // distributed across the 4 waves (round-1 lesson: never serialize on wave0)
    for (int rr = wid; rr < 32; rr += 4) {
        if (rowovf[rr] == 0) continue;
        const float* zrow = z + (size_t)(rowBase + rr) * HH;
        float bd = FLT_MAX; int bc = 0x7fffffff;
        for (int kq = 0; kq < 64; ++kq) {
            int c = (kq << 6) + lane;
            const float* wr = w + (size_t)c * HH;
            float dot = 0.f;
            for (int h4 = 0; h4 < 32; ++h4) {
                float4 wv = *reinterpret_cast<const float4*>(wr + (h4 << 2));
                float4 zv = *reinterpret_cast<const float4*>(zrow + (h4 << 2));
                dot = fmaf(zv.x,wv.x,dot); dot = fmaf(zv.y,wv.y,dot);
                dot = fmaf(zv.z,wv.z,dot); dot = fmaf(zv.w,wv.w,dot);
            }
            int co = c & 31;
            float wq2v = swq[((c >> 5) << 5) + (((co >> 2) & 1) << 4)
                             + ((co & 3) | ((co >> 3) << 2))];
            float d2 = wq2v - dot;
            if (d2 < bd || (d2 == bd && c < bc)) { bd = d2; bc = c; }
        }
#pragma unroll
        for (int off = 1; off < 64; off <<= 1) {
            float od = __shfl_xor(bd, off, 64);
            int oc = __shfl_xor(bc, off, 64);
            if (od < bd || (od == bd && oc < bc)) { bd = od; bc = oc; }
        }
        if (lane == 0) { fb[rr] = bc; out_idx[rowBase + rr] = (float)bc; }
    }
    __syncthreads();

    // ---- zq gather + loss (proven epilogue) ----
    const float4* z4 = reinterpret_cast<const float4*>(z);
    float lsum = 0.f;
#pragma unroll
    for (int i = 0; i < 4; ++i) {
        int g = i * 256 + t;
        int r = g >> 5, f4 = g & 31;
        int code = fb[r];
        float4 wv = *reinterpret_cast<const float4*>(w + (size_t)code * HH + (f4 << 2));
        float4 zv = z4[(size_t)(rowBase + r) * 32 + f4];
        float dx = wv.x - zv.x, dy = wv.y - zv.y, dz = wv.z - zv.z, dw = wv.w - zv.w;
        lsum = fmaf(dx, dx, lsum); lsum = fmaf(dy, dy, lsum);
        lsum = fmaf(dz, dz, lsum); lsum = fmaf(dw, dw, lsum);
        *reinterpret_cast<float4*>(out_zq + (size_t)(rowBase + r) * HH + (f4 << 2)) = wv;
    }
#pragma unroll
    for (int off = 1; off < 64; off <<= 1) lsum += __shfl_xor(lsum, off, 64);
    if (lane == 0) lred[wid] = lsum;
    __syncthreads();
    if (t == 0) {
        float total = lred[0] + lred[1] + lred[2] + lred[3];
        atomicAdd(out_loss, total * (1.25f / 4194304.0f));  // (0.25+1)*mean, N*H
    }
}

// ---------------- fallback path (Round-2 kernels, proven) -------------------
__device__ __forceinline__ int plane_off_fb(int r, int hu) {
    return ((hu << 6) | (r ^ (hu & 7))) << 3;
}

__global__ __launch_bounds__(256) void vq_prep_fb(const float* __restrict__ w,
                                                  float* __restrict__ wsq,
                                                  float* __restrict__ loss_slot) {
    int c = blockIdx.x * 256 + threadIdx.x;
    if (c == 0) loss_slot[0] = 0.0f;
    if (c < KCODES) {
        const float4* row = reinterpret_cast<const float4*>(w + (size_t)c * HH);
        float s = 0.0f;
#pragma unroll
        for (int i = 0; i < HH / 4; ++i) {
            float4 v = row[i];
            s = fmaf(v.x, v.x, s); s = fmaf(v.y, v.y, s);
            s = fmaf(v.z, v.z, s); s = fmaf(v.w, v.w, s);
        }
        wsq[c] = s;
    }
}

__device__ __forceinline__ void stage_tile_fb(const float4* __restrict__ src4,
                                              ushort* lds, int hi_base, int lo_base,
                                              int t) {
#pragma unroll
    for (int p = 0; p < 8; ++p) {
        int g = p * 256 + t;
        int r = g >> 5, f4 = g & 31;
        float4 v = src4[g];
        _Float16 h0 = (_Float16)v.x, h1 = (_Float16)v.y,
                 h2 = (_Float16)v.z, h3 = (_Float16)v.w;
        half4_t hv = {h0, h1, h2, h3};
        half4_t lv = {(_Float16)(v.x - (float)h0), (_Float16)(v.y - (float)h1),
                      (_Float16)(v.z - (float)h2), (_Float16)(v.w - (float)h3)};
        int off = plane_off_fb(r, f4 >> 1) + ((f4 & 1) << 2);
        *reinterpret_cast<half4_t*>(&lds[hi_base + off]) = hv;
        *reinterpret_cast<half4_t*>(&lds[lo_base + off]) = lv;
    }
}

__global__ __launch_bounds__(256, 2) void vq_main_fb(const float* __restrict__ z,
                                                     const float* __restrict__ w,
                                                     const float* __restrict__ wsq,
                                                     float* __restrict__ out_zq,
                                                     float* __restrict__ out_idx,
                                                     float* __restrict__ out_loss) {
    __shared__ __align__(16) ushort lds[32768];
    const int t = threadIdx.x, lane = t & 63, wid = t >> 6;
    const int q = lane >> 4, m15 = lane & 15;
    const int wrow = (wid >> 1) << 5, wcol = (wid & 1) << 5;
    const int rowBase = blockIdx.x * 64;

    stage_tile_fb(reinterpret_cast<const float4*>(z + (size_t)rowBase * HH), lds, 0, 8192, t);

    float best[2][4]; int bidx[2][4];
#pragma unroll
    for (int mt = 0; mt < 2; ++mt)
#pragma unroll
        for (int rg = 0; rg < 4; ++rg) { best[mt][rg] = FLT_MAX; bidx[mt][rg] = 0; }

    const int ar0 = wrow + m15, bn0 = wcol + m15;

    for (int k0 = 0; k0 < KCODES; k0 += 64) {
        __syncthreads();
        stage_tile_fb(reinterpret_cast<const float4*>(w + (size_t)k0 * HH), lds, 16384, 24576, t);
        __syncthreads();
        floatx4 acc[2][2];
#pragma unroll
        for (int mt = 0; mt < 2; ++mt)
#pragma unroll
            for (int nt = 0; nt < 2; ++nt) acc[mt][nt] = (floatx4){0.f, 0.f, 0.f, 0.f};
#pragma unroll
        for (int c = 0; c < 4; ++c) {
            const int hu = (c << 2) + q;
            half8 zh0 = *reinterpret_cast<half8*>(&lds[plane_off_fb(ar0, hu)]);
            half8 zh1 = *reinterpret_cast<half8*>(&lds[plane_off_fb(ar0 + 16, hu)]);
            half8 zl0 = *reinterpret_cast<half8*>(&lds[8192 + plane_off_fb(ar0, hu)]);
            half8 zl1 = *reinterpret_cast<half8*>(&lds[8192 + plane_off_fb(ar0 + 16, hu)]);
            half8 wh0 = *reinterpret_cast<half8*>(&lds[16384 + plane_off_fb(bn0, hu)]);
            half8 wh1 = *reinterpret_cast<half8*>(&lds[16384 + plane_off_fb(bn0 + 16, hu)]);
            half8 wl0 = *reinterpret_cast<half8*>(&lds[24576 + plane_off_fb(bn0, hu)]);
            half8 wl1 = *reinterpret_cast<half8*>(&lds[24576 + plane_off_fb(bn0 + 16, hu)]);
            acc[0][0] = __builtin_amdgcn_mfma_f32_16x16x32_f16(zh0, wh0, acc[0][0], 0, 0, 0);
            acc[0][1] = __builtin_amdgcn_mfma_f32_16x16x32_f16(zh0, wh1, acc[0][1], 0, 0, 0);
            acc[1][0] = __builtin_amdgcn_mfma_f32_16x16x32_f16(zh1, wh0, acc[1][0], 0, 0, 0);
            acc[1][1] = __builtin_amdgcn_mfma_f32_16x16x32_f16(zh1, wh1, acc[1][1], 0, 0, 0);
            acc[0][0] = __builtin_amdgcn_mfma_f32_16x16x32_f16(zh0, wl0, acc[0][0], 0, 0, 0);
            acc[0][1] = __builtin_amdgcn_mfma_f32_16x16x32_f16(zh0, wl1, acc[0][1], 0, 0, 0);
            acc[1][0] = __builtin_amdgcn_mfma_f32_16x16x32_f16(zh1, wl0, acc[1][0], 0, 0, 0);
            acc[1][1] = __builtin_amdgcn_mfma_f32_16x16x32_f16(zh1, wl1, acc[1][1], 0, 0, 0);
            acc[0][0] = __builtin_amdgcn_mfma_f32_16x16x32_f16(zl0, wh0, acc[0][0], 0, 0, 0);
            acc[0][1] = __builtin_amdgcn_mfma_f32_16x16x32_f16(zl0, wh1, acc[0][1], 0, 0, 0);
            acc[1][0] = __builtin_amdgcn_mfma_f32_16x16x32_f16(zl1, wh0, acc[1][0], 0, 0, 0);
            acc[1][1] = __builtin_amdgcn_mfma_f32_16x16x32_f16(zl1, wh1, acc[1][1], 0, 0, 0);
        }
        float wq0 = wsq[k0 + bn0], wq1 = wsq[k0 + bn0 + 16];
#pragma unroll
        for (int mt = 0; mt < 2; ++mt)
#pragma unroll
            for (int nt = 0; nt < 2; ++nt) {
                int code = k0 + wcol + (nt << 4) + m15;
                float wqv = nt ? wq1 : wq0;
#pragma unroll
                for (int rg = 0; rg < 4; ++rg) {
                    float s = fmaf(-2.0f, acc[mt][nt][rg], wqv);
                    if (s < best[mt][rg]) { best[mt][rg] = s; bidx[mt][rg] = code; }
                }
            }
    }
#pragma unroll
    for (int off = 1; off < 16; off <<= 1)
#pragma unroll
        for (int mt = 0; mt < 2; ++mt)
#pragma unroll
            for (int rg = 0; rg < 4; ++rg) {
                float os = __shfl_xor(best[mt][rg], off, 64);
                int   oi = __shfl_xor(bidx[mt][rg], off, 64);
                if (os < best[mt][rg] || (os == best[mt][rg] && oi < bidx[mt][rg])) {
                    best[mt][rg] = os; bidx[mt][rg] = oi;
                }
            }
    float* epmin = reinterpret_cast<float*>(lds);
    int*   epidx = reinterpret_cast<int*>(reinterpret_cast<char*>(lds) + 512);
    int*   fbidx = reinterpret_cast<int*>(reinterpret_cast<char*>(lds) + 1024);
    float* lredf = reinterpret_cast<float*>(reinterpret_cast<char*>(lds) + 1280);
    __syncthreads();
    if (m15 == 0) {
        int g = wid & 1;
#pragma unroll
        for (int mt = 0; mt < 2; ++mt)
#pragma unroll
            for (int rg = 0; rg < 4; ++rg) {
                int row = wrow + (mt << 4) + (q << 2) + rg;
                epmin[g * 64 + row] = best[mt][rg];
                epidx[g * 64 + row] = bidx[mt][rg];
            }
    }
    __syncthreads();
    if (t < 64) {
        float s0 = epmin[t], s1 = epmin[64 + t];
        int   i0 = epidx[t], i1 = epidx[64 + t];
        int   fi = (s1 < s0 || (s1 == s0 && i1 < i0)) ? i1 : i0;
        fbidx[t] = fi;
        out_idx[rowBase + t] = (float)fi;
    }
    __syncthreads();
    const float4* z4 = reinterpret_cast<const float4*>(z);
    float lsum = 0.0f;
#pragma unroll
    for (int i = 0; i < 8; ++i) {
        int g = i * 256 + t;
        int r = g >> 5, f4 = g & 31;
        int code = fbidx[r];
        float4 wv = *reinterpret_cast<const float4*>(w + (size_t)code * HH + (f4 << 2));
        float4 zv = z4[(size_t)(rowBase + r) * 32 + f4];
        float dx = wv.x - zv.x, dy = wv.y - zv.y, dz = wv.z - zv.z, dw = wv.w - zv.w;
        lsum = fmaf(dx, dx, lsum); lsum = fmaf(dy, dy, lsum);
        lsum = fmaf(dz, dz, lsum); lsum = fmaf(dw, dw, lsum);
        *reinterpret_cast<float4*>(out_zq + (size_t)(rowBase + r) * HH + (f4 << 2)) = wv;
    }
#pragma unroll
    for (int off = 1; off < 64; off <<= 1) lsum += __shfl_xor(lsum, off, 64);
    if (lane == 0) lredf[wid] = lsum;
    __syncthreads();
    if (t == 0)
        atomicAdd(out_loss, (lredf[0] + lredf[1] + lredf[2] + lredf[3]) * (1.25f / 4194304.0f));
}

extern "C" void kernel_launch(void* const* d_in, const int* in_sizes, int n_in,
                              void* d_out, int out_size, void* d_ws, size_t ws_size,
                              hipStream_t stream) {
    (void)in_sizes; (void)n_in; (void)out_size;
    const float* z = (const float*)d_in[0];
    const float* w = (const float*)d_in[1];
    float* out      = (float*)d_out;
    float* out_zq   = out;
    float* out_idx  = out + (size_t)NROWS * HH;
    float* out_loss = out_idx + NROWS;

    char* wsb = (char*)d_ws;
    float* wq2R   = (float*)(wsb + 0);        // 16 KB
    float* whPart = (float*)(wsb + 16384);    // 2 KB (512 floats)
    char*  whiA   = (char*)(wsb + 18432);     // 512 KB i8 codes, A-frag order
    const size_t WS_NEED = 18432 + (size_t)KCODES * HH;

    if (ws_size >= WS_NEED) {
        vq_prep<<<256, 256, 0, stream>>>(w, wq2R, whiA, whPart, out_loss);
        vq_fused<<<NROWS / 32, 256, 0, stream>>>(z, w, wq2R, whiA, whPart,
                                                 out_zq, out_idx, out_loss);
    } else {
        float* wsq = (float*)d_ws;
        vq_prep_fb<<<KCODES / 256, 256, 0, stream>>>(w, wsq, out_loss);
        vq_main_fb<<<NROWS / 64, 256, 0, stream>>>(z, w, wsq, out_zq, out_idx, out_loss);
    }
}

// Round 3
// 134.955 us; speedup vs baseline: 3.7180x; 1.3200x over previous
//
#include <hip/hip_runtime.h>
#include <float.h>
#include <stdint.h>

#define HH 128
#define NROWS 32768
#define KCODES 4096
#define CAPR 40

typedef _Float16 half8 __attribute__((ext_vector_type(8)));
typedef _Float16 half4_t __attribute__((ext_vector_type(4)));
typedef float floatx4 __attribute__((ext_vector_type(4)));
typedef float floatx16 __attribute__((ext_vector_type(16)));

// order-preserving float<->uint key (handles negatives) for LDS atomicMin
__device__ __forceinline__ unsigned fkey(float f) {
    unsigned b = __float_as_uint(f);
    return b ^ ((unsigned)((int)b >> 31) | 0x80000000u);
}
__device__ __forceinline__ float funkey(unsigned k) {
    unsigned b = (k & 0x80000000u) ? (k ^ 0x80000000u) : ~k;
    return __uint_as_float(b);
}

// ---------------------------------------------------------------------------
// ws layout (bytes): 0 wq2R float[4096] (0.5*||w||^2 in MFMA C-register
// order) | 16384 whPart float[256] | 17408 whiA ushort[524288] (1 MB,
// A-frag order). whiA: chunk (cb = code>>5, s = h/16) = 512 ushorts; entry
// lane = kh*32 + (code&31) holds w_hi[code][s*16 + kh*8 .. +8] (round-0
// validated). wq2R[cb*32 + kh*16 + r] = 0.5*||w||^2 of code
// cb*32+(r&3)+8*(r>>2)+4*kh (m74/m101 C/D layout).
// ---------------------------------------------------------------------------

__global__ __launch_bounds__(256) void vq_prep(const float* __restrict__ w,
        float* __restrict__ wq2R, ushort* __restrict__ whiA,
        float* __restrict__ whPart, float* __restrict__ loss_slot) {
    __shared__ float sWH[16];
    const int t = threadIdx.x;
    const int tid = blockIdx.x * 256 + t;
    if (tid == 0) loss_slot[0] = 0.0f;   // d_out poisoned 0xAA each launch
    const int c = tid >> 4, hg = tid & 15, s = hg >> 1, khh = hg & 1;

    const float4* src = reinterpret_cast<const float4*>(w + (size_t)c * HH + (hg << 3));
    float4 a = src[0], b = src[1];
    _Float16 h0=(_Float16)a.x, h1=(_Float16)a.y, h2=(_Float16)a.z, h3=(_Float16)a.w;
    _Float16 h4=(_Float16)b.x, h5=(_Float16)b.y, h6=(_Float16)b.z, h7=(_Float16)b.w;
    half8 hi = {h0, h1, h2, h3, h4, h5, h6, h7};
    *reinterpret_cast<half8*>(&whiA[((size_t)(c >> 5) * 8 + s) * 512 +
                                    (((khh << 5) | (c & 31)) << 3)]) = hi;

    float ssq = 0.f;
    ssq = fmaf(a.x, a.x, ssq); ssq = fmaf(a.y, a.y, ssq);
    ssq = fmaf(a.z, a.z, ssq); ssq = fmaf(a.w, a.w, ssq);
    ssq = fmaf(b.x, b.x, ssq); ssq = fmaf(b.y, b.y, ssq);
    ssq = fmaf(b.z, b.z, ssq); ssq = fmaf(b.w, b.w, ssq);
    ssq += __shfl_xor(ssq, 1, 64);
    ssq += __shfl_xor(ssq, 2, 64);
    ssq += __shfl_xor(ssq, 4, 64);
    ssq += __shfl_xor(ssq, 8, 64);
    if (hg == 0) {
        int co = c & 31;
        wq2R[((c >> 5) << 5) + (((co >> 2) & 1) << 4) + ((co & 3) | ((co >> 3) << 2))]
            = 0.5f * ssq;
        sWH[t >> 4] = ssq;
    }
    __syncthreads();
    if (t == 0) {
        float mh = 0.f;
#pragma unroll
        for (int i = 0; i < 16; ++i) mh = fmaxf(mh, sWH[i]);
        whPart[blockIdx.x] = mh;
    }
}

// ---------------------------------------------------------------------------
// Fused: hi-fp16 candidate-collecting scan, 64 rows/block (two B-fragments
// share each A-fragment read -> per-row fragment traffic halved vs round-0),
// wq2 C-init from LDS, register-only trigger pre-check, reserve-then-store
// collection, exact fp32 eval + zq/loss epilogue. 4 waves x 1024-code
// quarters; codes-as-M (A), z rows as B (lane-resident).
// ---------------------------------------------------------------------------
__global__ __launch_bounds__(256, 2) void vq_fused(
        const float* __restrict__ z, const float* __restrict__ w,
        const float* __restrict__ wq2R, const ushort* __restrict__ whiA,
        const float* __restrict__ whPart,
        float* __restrict__ out_zq, float* __restrict__ out_idx,
        float* __restrict__ out_loss) {
    __shared__ unsigned smin[64];
    __shared__ int rowcnt[64];
    __shared__ int rowovf[64];
    __shared__ int rowlist[64 * CAPR];
    __shared__ float swh[4];
    __shared__ int fb[64];
    __shared__ float lred[4];
    __shared__ __align__(16) float swq[KCODES];   // 16 KB wq2R copy

    const int t = threadIdx.x;
    const int lane = t & 63, wid = t >> 6;
    const int n = lane & 31, kh = lane >> 5;
    const int rowBase = blockIdx.x * 64;

    // codebook max ||w||^2 partial reduce (256 partials from prep)
    float wp = whPart[t];
#pragma unroll
    for (int off = 1; off < 64; off <<= 1) wp = fmaxf(wp, __shfl_xor(wp, off, 64));
    if (lane == 0) swh[wid] = wp;
    if (t < 64) { smin[t] = 0xFFFFFFFFu; rowcnt[t] = 0; rowovf[t] = 0; }

    // stage wq2R into LDS (scan C-init reads become broadcast ds_reads)
    {
        const float4* g4 = reinterpret_cast<const float4*>(wq2R);
        float4* s4 = reinterpret_cast<float4*>(swq);
#pragma unroll
        for (int i = 0; i < 4; ++i) s4[i * 256 + t] = g4[i * 256 + t];
    }

    // ---- stage z: NEGATED hi fp16 B-frags for rows n and n+32 + norms ----
    half8 zbA[8], zbB[8];
    float zn2A = 0.f, zl2A = 0.f, zn2B = 0.f, zl2B = 0.f;
    {
        const float* zr = z + (size_t)(rowBase + n) * HH + (kh << 3);
#pragma unroll
        for (int s = 0; s < 8; ++s) {
            float4 a = *reinterpret_cast<const float4*>(zr + (s << 4));
            float4 b = *reinterpret_cast<const float4*>(zr + (s << 4) + 4);
            _Float16 h0=(_Float16)a.x, h1=(_Float16)a.y, h2=(_Float16)a.z, h3=(_Float16)a.w;
            _Float16 h4=(_Float16)b.x, h5=(_Float16)b.y, h6=(_Float16)b.z, h7=(_Float16)b.w;
            zbA[s] = (half8){-h0, -h1, -h2, -h3, -h4, -h5, -h6, -h7};
            zn2A = fmaf(a.x,a.x,zn2A); zn2A = fmaf(a.y,a.y,zn2A);
            zn2A = fmaf(a.z,a.z,zn2A); zn2A = fmaf(a.w,a.w,zn2A);
            zn2A = fmaf(b.x,b.x,zn2A); zn2A = fmaf(b.y,b.y,zn2A);
            zn2A = fmaf(b.z,b.z,zn2A); zn2A = fmaf(b.w,b.w,zn2A);
            float l0=a.x-(float)h0, l1=a.y-(float)h1, l2=a.z-(float)h2, l3=a.w-(float)h3;
            float l4=b.x-(float)h4, l5=b.y-(float)h5, l6=b.z-(float)h6, l7=b.w-(float)h7;
            zl2A = fmaf(l0,l0,zl2A); zl2A = fmaf(l1,l1,zl2A);
            zl2A = fmaf(l2,l2,zl2A); zl2A = fmaf(l3,l3,zl2A);
            zl2A = fmaf(l4,l4,zl2A); zl2A = fmaf(l5,l5,zl2A);
            zl2A = fmaf(l6,l6,zl2A); zl2A = fmaf(l7,l7,zl2A);
        }
        const float* zr2 = z + (size_t)(rowBase + 32 + n) * HH + (kh << 3);
#pragma unroll
        for (int s = 0; s < 8; ++s) {
            float4 a = *reinterpret_cast<const float4*>(zr2 + (s << 4));
            float4 b = *reinterpret_cast<const float4*>(zr2 + (s << 4) + 4);
            _Float16 h0=(_Float16)a.x, h1=(_Float16)a.y, h2=(_Float16)a.z, h3=(_Float16)a.w;
            _Float16 h4=(_Float16)b.x, h5=(_Float16)b.y, h6=(_Float16)b.z, h7=(_Float16)b.w;
            zbB[s] = (half8){-h0, -h1, -h2, -h3, -h4, -h5, -h6, -h7};
            zn2B = fmaf(a.x,a.x,zn2B); zn2B = fmaf(a.y,a.y,zn2B);
            zn2B = fmaf(a.z,a.z,zn2B); zn2B = fmaf(a.w,a.w,zn2B);
            zn2B = fmaf(b.x,b.x,zn2B); zn2B = fmaf(b.y,b.y,zn2B);
            zn2B = fmaf(b.z,b.z,zn2B); zn2B = fmaf(b.w,b.w,zn2B);
            float l0=a.x-(float)h0, l1=a.y-(float)h1, l2=a.z-(float)h2, l3=a.w-(float)h3;
            float l4=b.x-(float)h4, l5=b.y-(float)h5, l6=b.z-(float)h6, l7=b.w-(float)h7;
            zl2B = fmaf(l0,l0,zl2B); zl2B = fmaf(l1,l1,zl2B);
            zl2B = fmaf(l2,l2,zl2B); zl2B = fmaf(l3,l3,zl2B);
            zl2B = fmaf(l4,l4,zl2B); zl2B = fmaf(l5,l5,zl2B);
            zl2B = fmaf(l6,l6,zl2B); zl2B = fmaf(l7,l7,zl2B);
        }
        zn2A += __shfl_xor(zn2A, 32, 64);
        zl2A += __shfl_xor(zl2A, 32, 64);
        zn2B += __shfl_xor(zn2B, 32, 64);
        zl2B += __shfl_xor(zl2B, 32, 64);
    }
    __syncthreads();   // smin/cnt init + swh + swq visible

    // rigorous window: |d/2_true - sc| <= E; accept if sc < runmin + thrw,
    // thrw > 2E  =>  true argmin always collected; non-collected strictly worse
    float WH = sqrtf(fmaxf(fmaxf(swh[0], swh[1]), fmaxf(swh[2], swh[3])));
    float thrwA, thrwB;
    {
        float znr = sqrtf(zn2A), zlr = sqrtf(zl2A);
        float E = zlr * WH * 1.01f + (znr + zlr) * (WH * 4.8828125e-4f + 1e-6f) + 4e-3f;
        thrwA = 2.0f * E * 1.05f + 0.01f;
        float znr2 = sqrtf(zn2B), zlr2 = sqrtf(zl2B);
        float E2 = zlr2 * WH * 1.01f + (znr2 + zlr2) * (WH * 4.8828125e-4f + 1e-6f) + 4e-3f;
        thrwB = 2.0f * E2 * 1.05f + 0.01f;
    }

    const half8* A8 = reinterpret_cast<const half8*>(whiA);
    const int cb0 = wid << 5;
    float m1A = FLT_MAX, m1pA = FLT_MAX, m1B = FLT_MAX, m1pB = FLT_MAX;

    half8 afA[8], afB[8];
    {
        const half8* ap = A8 + ((size_t)cb0 << 3) * 64 + lane;
#pragma unroll
        for (int p = 0; p < 8; ++p) afA[p] = ap[p * 64];
    }

    // per-row-group scan epilogue: min-tree, bound check, rare collection
    auto proc = [&](int it, int cb, const floatx16& acc, float& m1, float& m1pub,
                    float thrw, int row) {
        float t00=fminf(acc[0],acc[1]),   t01=fminf(acc[2],acc[3]);
        float t02=fminf(acc[4],acc[5]),   t03=fminf(acc[6],acc[7]);
        float t04=fminf(acc[8],acc[9]),   t05=fminf(acc[10],acc[11]);
        float t06=fminf(acc[12],acc[13]), t07=fminf(acc[14],acc[15]);
        float tmin = fminf(fminf(fminf(t00,t01), fminf(t02,t03)),
                           fminf(fminf(t04,t05), fminf(t06,t07)));
        m1 = fminf(m1, tmin);
        if (m1 < m1pub) { atomicMin(&smin[row], fkey(m1)); m1pub = m1; }
        // register-only pre-check: shared bound <= local bound, so a local
        // fail proves no candidate here (m1 already includes this tile)
        if (it > 0 && tmin < m1 + thrw) {
            float sh = funkey(((volatile unsigned*)smin)[row]);
            float bound = fminf(sh, m1) + thrw;
            if (tmin < bound) {
                unsigned cm = 0;
#pragma unroll
                for (int r = 0; r < 16; ++r)
                    if (acc[r] < bound) cm |= (1u << r);
                int cc = __popc(cm);
                int ix = atomicAdd(&rowcnt[row], cc);
                if (ix + cc > CAPR) rowovf[row] = 1;
#pragma unroll
                for (int r = 0; r < 16; ++r) {
                    if (cm & (1u << r)) {
                        if (ix < CAPR)
                            rowlist[row * CAPR + ix] =
                                (cb << 5) + (r & 3) + ((r >> 2) << 3) + (kh << 2);
                        ++ix;
                    }
                }
            }
        }
    };

    auto body = [&](int it, half8 (&cur)[8], half8 (&nxt)[8]) {
        const int cb = cb0 + ((it < 32) ? it : 0);
        if (it < 32) {
            const int cbn = cb0 + ((it + 1) & 31);
            const half8* ap = A8 + ((size_t)cbn << 3) * 64 + lane;
#pragma unroll
            for (int p = 0; p < 8; ++p) nxt[p] = ap[p * 64];
        }
        // C-init from LDS wq2 (broadcast, conflict-free): acc = d/2 estimate
        floatx16 wqc = *reinterpret_cast<const floatx16*>(&swq[(cb << 5) + (kh << 4)]);
        floatx16 a0 = __builtin_amdgcn_mfma_f32_32x32x16_f16(cur[0], zbA[0], wqc, 0, 0, 0);
        floatx16 a1 = __builtin_amdgcn_mfma_f32_32x32x16_f16(cur[0], zbB[0], wqc, 0, 0, 0);
#pragma unroll
        for (int s = 1; s < 8; ++s) {
            a0 = __builtin_amdgcn_mfma_f32_32x32x16_f16(cur[s], zbA[s], a0, 0, 0, 0);
            a1 = __builtin_amdgcn_mfma_f32_32x32x16_f16(cur[s], zbB[s], a1, 0, 0, 0);
        }
        proc(it, cb, a0, m1A, m1pA, thrwA, n);
        proc(it, cb, a1, m1B, m1pB, thrwB, n + 32);
    };

#pragma unroll 1
    for (int itp = 0; itp < 16; ++itp) {
        body(2 * itp,     afA, afB);
        body(2 * itp + 1, afB, afA);
    }
    body(32, afA, afB);   // re-pass tile 0 (warm bound)
    __syncthreads();

    // ---- exact fp32 eval of candidates (4 threads per row, 64 rows) ----
    {
        const int erow = t >> 2, eq = t & 3;
        int cnt = rowcnt[erow];
        bool ovf = (rowovf[erow] != 0) || (cnt > CAPR) || (cnt == 0);
        if (cnt > CAPR) cnt = CAPR;
        if (ovf) {
            if (eq == 0) rowovf[erow] = 1;
        } else {
            const float* zs = z + (size_t)(rowBase + erow) * HH + (eq << 5);
            float4 z0 = *reinterpret_cast<const float4*>(zs);
            float4 z1 = *reinterpret_cast<const float4*>(zs + 4);
            float4 z2 = *reinterpret_cast<const float4*>(zs + 8);
            float4 z3 = *reinterpret_cast<const float4*>(zs + 12);
            float4 z4v = *reinterpret_cast<const float4*>(zs + 16);
            float4 z5 = *reinterpret_cast<const float4*>(zs + 20);
            float4 z6 = *reinterpret_cast<const float4*>(zs + 24);
            float4 z7 = *reinterpret_cast<const float4*>(zs + 28);
            float bd = FLT_MAX; int bc = 0x7fffffff;
            for (int j = 0; j < cnt; ++j) {
                int c = rowlist[erow * CAPR + j];
                const float* wr = w + (size_t)c * HH + (eq << 5);
                float4 w0 = *reinterpret_cast<const float4*>(wr);
                float4 w1 = *reinterpret_cast<const float4*>(wr + 4);
                float4 w2 = *reinterpret_cast<const float4*>(wr + 8);
                float4 w3 = *reinterpret_cast<const float4*>(wr + 12);
                float4 w4 = *reinterpret_cast<const float4*>(wr + 16);
                float4 w5 = *reinterpret_cast<const float4*>(wr + 20);
                float4 w6 = *reinterpret_cast<const float4*>(wr + 24);
                float4 w7 = *reinterpret_cast<const float4*>(wr + 28);
                float dot = 0.f;
                dot = fmaf(z0.x,w0.x,dot); dot = fmaf(z0.y,w0.y,dot);
                dot = fmaf(z0.z,w0.z,dot); dot = fmaf(z0.w,w0.w,dot);
                dot = fmaf(z1.x,w1.x,dot); dot = fmaf(z1.y,w1.y,dot);
                dot = fmaf(z1.z,w1.z,dot); dot = fmaf(z1.w,w1.w,dot);
                dot = fmaf(z2.x,w2.x,dot); dot = fmaf(z2.y,w2.y,dot);
                dot = fmaf(z2.z,w2.z,dot); dot = fmaf(z2.w,w2.w,dot);
                dot = fmaf(z3.x,w3.x,dot); dot = fmaf(z3.y,w3.y,dot);
                dot = fmaf(z3.z,w3.z,dot); dot = fmaf(z3.w,w3.w,dot);
                dot = fmaf(z4v.x,w4.x,dot); dot = fmaf(z4v.y,w4.y,dot);
                dot = fmaf(z4v.z,w4.z,dot); dot = fmaf(z4v.w,w4.w,dot);
                dot = fmaf(z5.x,w5.x,dot); dot = fmaf(z5.y,w5.y,dot);
                dot = fmaf(z5.z,w5.z,dot); dot = fmaf(z5.w,w5.w,dot);
                dot = fmaf(z6.x,w6.x,dot); dot = fmaf(z6.y,w6.y,dot);
                dot = fmaf(z6.z,w6.z,dot); dot = fmaf(z6.w,w6.w,dot);
                dot = fmaf(z7.x,w7.x,dot); dot = fmaf(z7.y,w7.y,dot);
                dot = fmaf(z7.z,w7.z,dot); dot = fmaf(z7.w,w7.w,dot);
                dot += __shfl_xor(dot, 1, 64);
                dot += __shfl_xor(dot, 2, 64);
                int co = c & 31;
                float wq2v = swq[((c >> 5) << 5) + (((co >> 2) & 1) << 4)
                                 + ((co & 3) | ((co >> 3) << 2))];
                float d2 = wq2v - dot;
                if (d2 < bd || (d2 == bd && c < bc)) { bd = d2; bc = c; }
            }
            if (eq == 0) { fb[erow] = bc; out_idx[rowBase + erow] = (float)bc; }
        }
    }
    __syncthreads();

    // ---- rigorous fallback: full exact scan for overflow rows (~never),
    // rows distributed across the 4 waves ----
    for (int rr = wid; rr < 64; rr += 4) {
        if (rowovf[rr] == 0) continue;
        const float* zrow = z + (size_t)(rowBase + rr) * HH;
        float bd = FLT_MAX; int bc = 0x7fffffff;
        for (int kq = 0; kq < 64; ++kq) {
            int c = (kq << 6) + lane;
            const float* wr = w + (size_t)c * HH;
            float dot = 0.f;
            for (int h4 = 0; h4 < 32; ++h4) {
                float4 wv = *reinterpret_cast<const float4*>(wr + (h4 << 2));
                float4 zv = *reinterpret_cast<const float4*>(zrow + (h4 << 2));
                dot = fmaf(zv.x,wv.x,dot); dot = fmaf(zv.y,wv.y,dot);
                dot = fmaf(zv.z,wv.z,dot); dot = fmaf(zv.w,wv.w,dot);
            }
            int co = c & 31;
            float wq2v = swq[((c >> 5) << 5) + (((co >> 2) & 1) << 4)
                             + ((co & 3) | ((co >> 3) << 2))];
            float d2 = wq2v - dot;
            if (d2 < bd || (d2 == bd && c < bc)) { bd = d2; bc = c; }
        }
#pragma unroll
        for (int off = 1; off < 64; off <<= 1) {
            float od = __shfl_xor(bd, off, 64);
            int oc = __shfl_xor(bc, off, 64);
            if (od < bd || (od == bd && oc < bc)) { bd = od; bc = oc; }
        }
        if (lane == 0) { fb[rr] = bc; out_idx[rowBase + rr] = (float)bc; }
    }
    __syncthreads();

    // ---- zq gather + loss (proven epilogue) ----
    const float4* z4 = reinterpret_cast<const float4*>(z);
    float lsum = 0.f;
#pragma unroll
    for (int i = 0; i < 8; ++i) {
        int g = i * 256 + t;
        int r = g >> 5, f4 = g & 31;
        int code = fb[r];
        float4 wv = *reinterpret_cast<const float4*>(w + (size_t)code * HH + (f4 << 2));
        float4 zv = z4[(size_t)(rowBase + r) * 32 + f4];
        float dx = wv.x - zv.x, dy = wv.y - zv.y, dz = wv.z - zv.z, dw = wv.w - zv.w;
        lsum = fmaf(dx, dx, lsum); lsum = fmaf(dy, dy, lsum);
        lsum = fmaf(dz, dz, lsum); lsum = fmaf(dw, dw, lsum);
        *reinterpret_cast<float4*>(out_zq + (size_t)(rowBase + r) * HH + (f4 << 2)) = wv;
    }
#pragma unroll
    for (int off = 1; off < 64; off <<= 1) lsum += __shfl_xor(lsum, off, 64);
    if (lane == 0) lred[wid] = lsum;
    __syncthreads();
    if (t == 0) {
        float total = lred[0] + lred[1] + lred[2] + lred[3];
        atomicAdd(out_loss, total * (1.25f / 4194304.0f));  // (0.25+1)*mean, N*H
    }
}

// ---------------- fallback path (Round-2 kernels, proven) -------------------
__device__ __forceinline__ int plane_off_fb(int r, int hu) {
    return ((hu << 6) | (r ^ (hu & 7))) << 3;
}

__global__ __launch_bounds__(256) void vq_prep_fb(const float* __restrict__ w,
                                                  float* __restrict__ wsq,
                                                  float* __restrict__ loss_slot) {
    int c = blockIdx.x * 256 + threadIdx.x;
    if (c == 0) loss_slot[0] = 0.0f;
    if (c < KCODES) {
        const float4* row = reinterpret_cast<const float4*>(w + (size_t)c * HH);
        float s = 0.0f;
#pragma unroll
        for (int i = 0; i < HH / 4; ++i) {
            float4 v = row[i];
            s = fmaf(v.x, v.x, s); s = fmaf(v.y, v.y, s);
            s = fmaf(v.z, v.z, s); s = fmaf(v.w, v.w, s);
        }
        wsq[c] = s;
    }
}

__device__ __forceinline__ void stage_tile_fb(const float4* __restrict__ src4,
                                              ushort* lds, int hi_base, int lo_base,
                                              int t) {
#pragma unroll
    for (int p = 0; p < 8; ++p) {
        int g = p * 256 + t;
        int r = g >> 5, f4 = g & 31;
        float4 v = src4[g];
        _Float16 h0 = (_Float16)v.x, h1 = (_Float16)v.y,
                 h2 = (_Float16)v.z, h3 = (_Float16)v.w;
        half4_t hv = {h0, h1, h2, h3};
        half4_t lv = {(_Float16)(v.x - (float)h0), (_Float16)(v.y - (float)h1),
                      (_Float16)(v.z - (float)h2), (_Float16)(v.w - (float)h3)};
        int off = plane_off_fb(r, f4 >> 1) + ((f4 & 1) << 2);
        *reinterpret_cast<half4_t*>(&lds[hi_base + off]) = hv;
        *reinterpret_cast<half4_t*>(&lds[lo_base + off]) = lv;
    }
}

__global__ __launch_bounds__(256, 2) void vq_main_fb(const float* __restrict__ z,
                                                     const float* __restrict__ w,
                                                     const float* __restrict__ wsq,
                                                     float* __restrict__ out_zq,
                                                     float* __restrict__ out_idx,
                                                     float* __restrict__ out_loss) {
    __shared__ __align__(16) ushort lds[32768];
    const int t = threadIdx.x, lane = t & 63, wid = t >> 6;
    const int q = lane >> 4, m15 = lane & 15;
    const int wrow = (wid >> 1) << 5, wcol = (wid & 1) << 5;
    const int rowBase = blockIdx.x * 64;

    stage_tile_fb(reinterpret_cast<const float4*>(z + (size_t)rowBase * HH), lds, 0, 8192, t);

    float best[2][4]; int bidx[2][4];
#pragma unroll
    for (int mt = 0; mt < 2; ++mt)
#pragma unroll
        for (int rg = 0; rg < 4; ++rg) { best[mt][rg] = FLT_MAX; bidx[mt][rg] = 0; }

    const int ar0 = wrow + m15, bn0 = wcol + m15;

    for (int k0 = 0; k0 < KCODES; k0 += 64) {
        __syncthreads();
        stage_tile_fb(reinterpret_cast<const float4*>(w + (size_t)k0 * HH), lds, 16384, 24576, t);
        __syncthreads();
        floatx4 acc[2][2];
#pragma unroll
        for (int mt = 0; mt < 2; ++mt)
#pragma unroll
            for (int nt = 0; nt < 2; ++nt) acc[mt][nt] = (floatx4){0.f, 0.f, 0.f, 0.f};
#pragma unroll
        for (int c = 0; c < 4; ++c) {
            const int hu = (c << 2) + q;
            half8 zh0 = *reinterpret_cast<half8*>(&lds[plane_off_fb(ar0, hu)]);
            half8 zh1 = *reinterpret_cast<half8*>(&lds[plane_off_fb(ar0 + 16, hu)]);
            half8 zl0 = *reinterpret_cast<half8*>(&lds[8192 + plane_off_fb(ar0, hu)]);
            half8 zl1 = *reinterpret_cast<half8*>(&lds[8192 + plane_off_fb(ar0 + 16, hu)]);
            half8 wh0 = *reinterpret_cast<half8*>(&lds[16384 + plane_off_fb(bn0, hu)]);
            half8 wh1 = *reinterpret_cast<half8*>(&lds[16384 + plane_off_fb(bn0 + 16, hu)]);
            half8 wl0 = *reinterpret_cast<half8*>(&lds[24576 + plane_off_fb(bn0, hu)]);
            half8 wl1 = *reinterpret_cast<half8*>(&lds[24576 + plane_off_fb(bn0 + 16, hu)]);
            acc[0][0] = __builtin_amdgcn_mfma_f32_16x16x32_f16(zh0, wh0, acc[0][0], 0, 0, 0);
            acc[0][1] = __builtin_amdgcn_mfma_f32_16x16x32_f16(zh0, wh1, acc[0][1], 0, 0, 0);
            acc[1][0] = __builtin_amdgcn_mfma_f32_16x16x32_f16(zh1, wh0, acc[1][0], 0, 0, 0);
            acc[1][1] = __builtin_amdgcn_mfma_f32_16x16x32_f16(zh1, wh1, acc[1][1], 0, 0, 0);
            acc[0][0] = __builtin_amdgcn_mfma_f32_16x16x32_f16(zh0, wl0, acc[0][0], 0, 0, 0);
            acc[0][1] = __builtin_amdgcn_mfma_f32_16x16x32_f16(zh0, wl1, acc[0][1], 0, 0, 0);
            acc[1][0] = __builtin_amdgcn_mfma_f32_16x16x32_f16(zh1, wl0, acc[1][0], 0, 0, 0);
            acc[1][1] = __builtin_amdgcn_mfma_f32_16x16x32_f16(zh1, wl1, acc[1][1], 0, 0, 0);
            acc[0][0] = __builtin_amdgcn_mfma_f32_16x16x32_f16(zl0, wh0, acc[0][0], 0, 0, 0);
            acc[0][1] = __builtin_amdgcn_mfma_f32_16x16x32_f16(zl0, wh1, acc[0][1], 0, 0, 0);
            acc[1][0] = __builtin_amdgcn_mfma_f32_16x16x32_f16(zl1, wh0, acc[1][0], 0, 0, 0);
            acc[1][1] = __builtin_amdgcn_mfma_f32_16x16x32_f16(zl1, wh1, acc[1][1], 0, 0, 0);
        }
        float wq0 = wsq[k0 + bn0], wq1 = wsq[k0 + bn0 + 16];
#pragma unroll
        for (int mt = 0; mt < 2; ++mt)
#pragma unroll
            for (int nt = 0; nt < 2; ++nt) {
                int code = k0 + wcol + (nt << 4) + m15;
                float wqv = nt ? wq1 : wq0;
#pragma unroll
                for (int rg = 0; rg < 4; ++rg) {
                    float s = fmaf(-2.0f, acc[mt][nt][rg], wqv);
                    if (s < best[mt][rg]) { best[mt][rg] = s; bidx[mt][rg] = code; }
                }
            }
    }
#pragma unroll
    for (int off = 1; off < 16; off <<= 1)
#pragma unroll
        for (int mt = 0; mt < 2; ++mt)
#pragma unroll
            for (int rg = 0; rg < 4; ++rg) {
                float os = __shfl_xor(best[mt][rg], off, 64);
                int   oi = __shfl_xor(bidx[mt][rg], off, 64);
                if (os < best[mt][rg] || (os == best[mt][rg] && oi < bidx[mt][rg])) {
                    best[mt][rg] = os; bidx[mt][rg] = oi;
                }
            }
    float* epmin = reinterpret_cast<float*>(lds);
    int*   epidx = reinterpret_cast<int*>(reinterpret_cast<char*>(lds) + 512);
    int*   fbidx = reinterpret_cast<int*>(reinterpret_cast<char*>(lds) + 1024);
    float* lredf = reinterpret_cast<float*>(reinterpret_cast<char*>(lds) + 1280);
    __syncthreads();
    if (m15 == 0) {
        int g = wid & 1;
#pragma unroll
        for (int mt = 0; mt < 2; ++mt)
#pragma unroll
            for (int rg = 0; rg < 4; ++rg) {
                int row = wrow + (mt << 4) + (q << 2) + rg;
                epmin[g * 64 + row] = best[mt][rg];
                epidx[g * 64 + row] = bidx[mt][rg];
            }
    }
    __syncthreads();
    if (t < 64) {
        float s0 = epmin[t], s1 = epmin[64 + t];
        int   i0 = epidx[t], i1 = epidx[64 + t];
        int   fi = (s1 < s0 || (s1 == s0 && i1 < i0)) ? i1 : i0;
        fbidx[t] = fi;
        out_idx[rowBase + t] = (float)fi;
    }
    __syncthreads();
    const float4* z4 = reinterpret_cast<const float4*>(z);
    float lsum = 0.0f;
#pragma unroll
    for (int i = 0; i < 8; ++i) {
        int g = i * 256 + t;
        int r = g >> 5, f4 = g & 31;
        int code = fbidx[r];
        float4 wv = *reinterpret_cast<const float4*>(w + (size_t)code * HH + (f4 << 2));
        float4 zv = z4[(size_t)(rowBase + r) * 32 + f4];
        float dx = wv.x - zv.x, dy = wv.y - zv.y, dz = wv.z - zv.z, dw = wv.w - zv.w;
        lsum = fmaf(dx, dx, lsum); lsum = fmaf(dy, dy, lsum);
        lsum = fmaf(dz, dz, lsum); lsum = fmaf(dw, dw, lsum);
        *reinterpret_cast<float4*>(out_zq + (size_t)(rowBase + r) * HH + (f4 << 2)) = wv;
    }
#pragma unroll
    for (int off = 1; off < 64; off <<= 1) lsum += __shfl_xor(lsum, off, 64);
    if (lane == 0) lredf[wid] = lsum;
    __syncthreads();
    if (t == 0)
        atomicAdd(out_loss, (lredf[0] + lredf[1] + lredf[2] + lredf[3]) * (1.25f / 4194304.0f));
}

extern "C" void kernel_launch(void* const* d_in, const int* in_sizes, int n_in,
                              void* d_out, int out_size, void* d_ws, size_t ws_size,
                              hipStream_t stream) {
    (void)in_sizes; (void)n_in; (void)out_size;
    const float* z = (const float*)d_in[0];
    const float* w = (const float*)d_in[1];
    float* out      = (float*)d_out;
    float* out_zq   = out;
    float* out_idx  = out + (size_t)NROWS * HH;
    float* out_loss = out_idx + NROWS;

    char* wsb = (char*)d_ws;
    float*  wq2R   = (float*)(wsb + 0);        // 16 KB
    float*  whPart = (float*)(wsb + 16384);    // 1 KB
    ushort* whiA   = (ushort*)(wsb + 17408);   // 1 MB f16 codes, A-frag order
    const size_t WS_NEED = 17408 + (size_t)KCODES * HH * 2;

    if (ws_size >= WS_NEED) {
        vq_prep<<<256, 256, 0, stream>>>(w, wq2R, whiA, whPart, out_loss);
        vq_fused<<<NROWS / 64, 256, 0, stream>>>(z, w, wq2R, whiA, whPart,
                                                 out_zq, out_idx, out_loss);
    } else {
        float* wsq = (float*)d_ws;
        vq_prep_fb<<<KCODES / 256, 256, 0, stream>>>(w, wsq, out_loss);
        vq_main_fb<<<NROWS / 64, 256, 0, stream>>>(z, w, wsq, out_zq, out_idx, out_loss);
    }
}